// Round 2
// baseline (1325.485 us; speedup 1.0000x reference)
//
#include <hip/hip_runtime.h>

typedef unsigned short u16;
typedef __attribute__((ext_vector_type(8))) short short8;
typedef __attribute__((ext_vector_type(4))) float f32x4;

#define DEVI static __device__ __forceinline__

DEVI u16 f2bf(float f) {
  unsigned u = __builtin_bit_cast(unsigned, f);
  u += 0x7FFFu + ((u >> 16) & 1u);   // RNE
  return (u16)(u >> 16);
}

DEVI void glds16(const void* g, void* l) {
  __builtin_amdgcn_global_load_lds(
      (const __attribute__((address_space(1))) unsigned*)g,
      (__attribute__((address_space(3))) unsigned*)l, 16, 0, 0);
}

// ---------------- transpose + f32->bf16 convert: W (K x N) -> WT (N x K) ----
__global__ void k_transpose_cvt(const float* __restrict__ W,
                                u16* __restrict__ WT, int K, int N) {
  __shared__ float t[32][33];
  int n0 = blockIdx.x * 32;
  int k0 = blockIdx.y * 32;
  int tx = threadIdx.x;  // 0..31
  int ty = threadIdx.y;  // 0..7
#pragma unroll
  for (int r = 0; r < 32; r += 8)
    t[ty + r][tx] = W[(size_t)(k0 + ty + r) * N + (n0 + tx)];
  __syncthreads();
#pragma unroll
  for (int r = 0; r < 32; r += 8)
    WT[(size_t)(n0 + ty + r) * K + (k0 + tx)] = f2bf(t[tx][ty + r]);
}

// ---------------- gather h rows at span starts/ends, cast to bf16 ----------
// span_idx is delivered as int32 (harness contract: integer -> const int*)
__global__ void k_gather(const float* __restrict__ h,
                         const int* __restrict__ span,
                         u16* __restrict__ xs, u16* __restrict__ xe) {
  int row = blockIdx.x;  // 0..511  (b*64+n)
  int b = row >> 6;
  int s = span[row * 2 + 0];
  int e = span[row * 2 + 1];
  const float* hs = h + ((size_t)b * 512 + s) * 768;
  const float* he = h + ((size_t)b * 512 + e) * 768;
  for (int d = threadIdx.x; d < 768; d += 256) {
    xs[(size_t)row * 768 + d] = f2bf(hs[d]);
    xe[(size_t)row * 768 + d] = f2bf(he[d]);
  }
}

// ---------------- generic bf16 MFMA GEMM: C = A * B (+bias)(relu) ----------
// A: M x K bf16 (lda), BT: N x K bf16 (ldb, pre-transposed weights)
// flags: bit0 = relu, bit1 = bf16 output (else f32). Tile 128x128, BK=64.
__global__ __launch_bounds__(256)
void k_gemm(const u16* __restrict__ A, int lda,
            const u16* __restrict__ BT, int ldb,
            const float* __restrict__ bias,
            void* __restrict__ C, int ldc,
            int K, int mtiles, int flags) {
  __shared__ __align__(16) u16 As[128 * 64];
  __shared__ __align__(16) u16 Bs[128 * 64];
  int tid = threadIdx.x;
  int lane = tid & 63;
  int wave = tid >> 6;
  int wr = (wave >> 1) * 64, wc = (wave & 1) * 64;
  int bx = blockIdx.x;
  int m0 = (bx % mtiles) * 128;
  int n0 = (bx / mtiles) * 128;
  const int lr = lane & 15, hi = lane >> 4;

  f32x4 acc[4][4] = {};

  for (int k0 = 0; k0 < K; k0 += 64) {
#pragma unroll
    for (int it = 0; it < 4; ++it) {
      int s = it * 256 + tid;     // 0..1023 16B-granules of the 128x64 tile
      int row = s >> 3, g = s & 7;
      int gc = (g ^ (row & 7)) * 8;  // pre-swizzled source column (elements)
      glds16(A + (size_t)(m0 + row) * lda + k0 + gc, (char*)As + s * 16);
      glds16(BT + (size_t)(n0 + row) * ldb + k0 + gc, (char*)Bs + s * 16);
    }
    __syncthreads();
#pragma unroll
    for (int kk = 0; kk < 2; ++kk) {
      short8 af[4], bf[4];
      int gk = kk * 4 + hi;
#pragma unroll
      for (int m = 0; m < 4; ++m) {
        int row = wr + m * 16 + lr;
        af[m] = *(const short8*)((const char*)As + row * 128 + ((gk ^ (row & 7)) * 16));
      }
#pragma unroll
      for (int n = 0; n < 4; ++n) {
        int row = wc + n * 16 + lr;
        bf[n] = *(const short8*)((const char*)Bs + row * 128 + ((gk ^ (row & 7)) * 16));
      }
#pragma unroll
      for (int m = 0; m < 4; ++m)
#pragma unroll
        for (int n = 0; n < 4; ++n)
          acc[m][n] = __builtin_amdgcn_mfma_f32_16x16x32_bf16(af[m], bf[n], acc[m][n], 0, 0, 0);
    }
    __syncthreads();
  }

  bool relu = flags & 1, obf = flags & 2;
#pragma unroll
  for (int n = 0; n < 4; ++n) {
    int col = n0 + wc + n * 16 + lr;
    float bv = bias ? bias[col] : 0.f;
#pragma unroll
    for (int m = 0; m < 4; ++m) {
#pragma unroll
      for (int r = 0; r < 4; ++r) {
        int row = m0 + wr + m * 16 + hi * 4 + r;
        float v = acc[m][n][r] + bv;
        if (relu) v = fmaxf(v, 0.f);
        if (obf) ((u16*)C)[(size_t)row * ldc + col] = f2bf(v);
        else     ((float*)C)[(size_t)row * ldc + col] = v;
      }
    }
  }
}

// ---------------- fused pair GEMM: out[m] = relu(U[i]+V[j]) @ Wr2 + br2 ----
// M = 32256 (8 batches x 4032 pairs), N = 768, K = 6144.
// A tile (128x64) built on the fly from U,V (f32, br1 folded into U).
__global__ __launch_bounds__(256)
void k_pair_gemm(const float* __restrict__ U, const float* __restrict__ V,
                 const u16* __restrict__ Wr2T,  // 768 x 6144 bf16
                 const float* __restrict__ br2,
                 float* __restrict__ out) {
  __shared__ __align__(16) u16 As[128 * 64];
  __shared__ __align__(16) u16 Bs[128 * 64];
  int tid = threadIdx.x;
  int lane = tid & 63;
  int wave = tid >> 6;
  int wr = (wave >> 1) * 64, wc = (wave & 1) * 64;
  // XCD-aware swizzle: nwg = 1512 = 8*189; nt-major so each XCD walks
  // contiguous m-tiles (batch-coherent U/V reuse in its L2)
  int nwg = gridDim.x;
  int orig = blockIdx.x;
  int wgid = (orig & 7) * (nwg >> 3) + (orig >> 3);
  int mt = wgid % 252;
  int nt = wgid / 252;
  int m0 = mt * 128, n0 = nt * 128;
  const int lr = lane & 15, hi = lane >> 4;

  // A-staging prologue: thread owns row r, half q (32 cols)
  int r = tid >> 1, q = tid & 1;
  int mrow = m0 + r;
  int b = mrow / 4032;
  int p = mrow - b * 4032;
  int i = p / 63;
  int j0 = p - i * 63;
  int j = j0 + (j0 >= i ? 1 : 0);
  const float* uRow = U + (size_t)(b * 64 + i) * 6144;
  const float* vRow = V + (size_t)(b * 64 + j) * 6144;
  int qc = q * 32;

  f32x4 acc[4][4] = {};

  for (int k0 = 0; k0 < 6144; k0 += 64) {
    // B tile via async global->LDS (pre-swizzled source, linear dest)
#pragma unroll
    for (int it = 0; it < 4; ++it) {
      int s = it * 256 + tid;
      int row = s >> 3, g = s & 7;
      int gc = (g ^ (row & 7)) * 8;
      glds16(Wr2T + (size_t)(n0 + row) * 6144 + k0 + gc, (char*)Bs + s * 16);
    }
    // A tile via VALU: relu(U[i]+V[j]) -> bf16 -> swizzled ds_write
    float va[32];
#pragma unroll
    for (int w = 0; w < 8; ++w) {
      float4 uu = *(const float4*)(uRow + k0 + qc + w * 4);
      float4 vv = *(const float4*)(vRow + k0 + qc + w * 4);
      va[w * 4 + 0] = fmaxf(uu.x + vv.x, 0.f);
      va[w * 4 + 1] = fmaxf(uu.y + vv.y, 0.f);
      va[w * 4 + 2] = fmaxf(uu.z + vv.z, 0.f);
      va[w * 4 + 3] = fmaxf(uu.w + vv.w, 0.f);
    }
#pragma unroll
    for (int g = 0; g < 4; ++g) {
      short8 pk;
#pragma unroll
      for (int e = 0; e < 8; ++e) pk[e] = (short)f2bf(va[g * 8 + e]);
      *(short8*)((char*)As + r * 128 + (((q * 4 + g) ^ (r & 7)) * 16)) = pk;
    }
    __syncthreads();
#pragma unroll
    for (int kk = 0; kk < 2; ++kk) {
      short8 af[4], bf[4];
      int gk = kk * 4 + hi;
#pragma unroll
      for (int m = 0; m < 4; ++m) {
        int row = wr + m * 16 + lr;
        af[m] = *(const short8*)((const char*)As + row * 128 + ((gk ^ (row & 7)) * 16));
      }
#pragma unroll
      for (int n = 0; n < 4; ++n) {
        int row = wc + n * 16 + lr;
        bf[n] = *(const short8*)((const char*)Bs + row * 128 + ((gk ^ (row & 7)) * 16));
      }
#pragma unroll
      for (int m = 0; m < 4; ++m)
#pragma unroll
        for (int n = 0; n < 4; ++n)
          acc[m][n] = __builtin_amdgcn_mfma_f32_16x16x32_bf16(af[m], bf[n], acc[m][n], 0, 0, 0);
    }
    __syncthreads();
  }

#pragma unroll
  for (int n = 0; n < 4; ++n) {
    int col = n0 + wc + n * 16 + lr;
    float bv = br2[col];
#pragma unroll
    for (int m = 0; m < 4; ++m) {
#pragma unroll
      for (int rg = 0; rg < 4; ++rg) {
        int row = m0 + wr + m * 16 + hi * 4 + rg;
        out[(size_t)row * 768 + col] = acc[m][n][rg] + bv;
      }
    }
  }
}

// ---------------- workspace layout (bytes) ---------------------------------
constexpr size_t OFF_Ws1T = 0;
constexpr size_t OFF_Ws2T = OFF_Ws1T + (size_t)3072 * 768 * 2;
constexpr size_t OFF_We1T = OFF_Ws2T + (size_t)768 * 3072 * 2;
constexpr size_t OFF_We2T = OFF_We1T + (size_t)3072 * 768 * 2;
constexpr size_t OFF_Wo1T = OFF_We2T + (size_t)768 * 3072 * 2;
constexpr size_t OFF_Wo2T = OFF_Wo1T + (size_t)6144 * 1536 * 2;
constexpr size_t OFF_Wr1T = OFF_Wo2T + (size_t)768 * 6144 * 2;
constexpr size_t OFF_Wr2T = OFF_Wr1T + (size_t)6144 * 1536 * 2;
constexpr size_t OFF_XS   = OFF_Wr2T + (size_t)768 * 6144 * 2;
constexpr size_t OFF_XE   = OFF_XS + (size_t)512 * 768 * 2;
constexpr size_t OFF_HS1  = OFF_XE + (size_t)512 * 768 * 2;
constexpr size_t OFF_HE1  = OFF_HS1 + (size_t)512 * 3072 * 2;
constexpr size_t OFF_CAT  = OFF_HE1 + (size_t)512 * 3072 * 2;
constexpr size_t OFF_ENTH = OFF_CAT + (size_t)512 * 1536 * 2;
constexpr size_t OFF_ENT  = OFF_ENTH + (size_t)512 * 6144 * 2;
constexpr size_t OFF_U    = OFF_ENT + (size_t)512 * 768 * 2;
constexpr size_t OFF_V    = OFF_U + (size_t)512 * 6144 * 4;

extern "C" void kernel_launch(void* const* d_in, const int* in_sizes, int n_in,
                              void* d_out, int out_size, void* d_ws, size_t ws_size,
                              hipStream_t stream) {
  const float* h = (const float*)d_in[0];
  const int* span = (const int*)d_in[1];   // int inputs arrive as int32
  const float* Ws1 = (const float*)d_in[2];
  const float* bs1 = (const float*)d_in[3];
  const float* Ws2 = (const float*)d_in[4];
  const float* bs2 = (const float*)d_in[5];
  const float* We1 = (const float*)d_in[6];
  const float* be1 = (const float*)d_in[7];
  const float* We2 = (const float*)d_in[8];
  const float* be2 = (const float*)d_in[9];
  const float* Wo1 = (const float*)d_in[10];
  const float* bo1 = (const float*)d_in[11];
  const float* Wo2 = (const float*)d_in[12];
  const float* bo2 = (const float*)d_in[13];
  const float* Wr1 = (const float*)d_in[14];
  const float* br1 = (const float*)d_in[15];
  const float* Wr2 = (const float*)d_in[16];
  const float* br2 = (const float*)d_in[17];

  char* ws = (char*)d_ws;
  u16* Ws1T = (u16*)(ws + OFF_Ws1T);
  u16* Ws2T = (u16*)(ws + OFF_Ws2T);
  u16* We1T = (u16*)(ws + OFF_We1T);
  u16* We2T = (u16*)(ws + OFF_We2T);
  u16* Wo1T = (u16*)(ws + OFF_Wo1T);
  u16* Wo2T = (u16*)(ws + OFF_Wo2T);
  u16* Wr1T = (u16*)(ws + OFF_Wr1T);
  u16* Wr2T = (u16*)(ws + OFF_Wr2T);
  u16* xs   = (u16*)(ws + OFF_XS);
  u16* xe   = (u16*)(ws + OFF_XE);
  u16* hs1  = (u16*)(ws + OFF_HS1);
  u16* he1  = (u16*)(ws + OFF_HE1);
  u16* cat  = (u16*)(ws + OFF_CAT);
  u16* enth = (u16*)(ws + OFF_ENTH);
  u16* ent  = (u16*)(ws + OFF_ENT);
  float* Uf = (float*)(ws + OFF_U);
  float* Vf = (float*)(ws + OFF_V);

  dim3 tb(32, 8);
  // W (KxN) -> WT (NxK) bf16
  k_transpose_cvt<<<dim3(3072 / 32, 768 / 32), tb, 0, stream>>>(Ws1, Ws1T, 768, 3072);
  k_transpose_cvt<<<dim3(768 / 32, 3072 / 32), tb, 0, stream>>>(Ws2, Ws2T, 3072, 768);
  k_transpose_cvt<<<dim3(3072 / 32, 768 / 32), tb, 0, stream>>>(We1, We1T, 768, 3072);
  k_transpose_cvt<<<dim3(768 / 32, 3072 / 32), tb, 0, stream>>>(We2, We2T, 3072, 768);
  k_transpose_cvt<<<dim3(6144 / 32, 1536 / 32), tb, 0, stream>>>(Wo1, Wo1T, 1536, 6144);
  k_transpose_cvt<<<dim3(768 / 32, 6144 / 32), tb, 0, stream>>>(Wo2, Wo2T, 6144, 768);
  k_transpose_cvt<<<dim3(6144 / 32, 1536 / 32), tb, 0, stream>>>(Wr1, Wr1T, 1536, 6144);
  k_transpose_cvt<<<dim3(768 / 32, 6144 / 32), tb, 0, stream>>>(Wr2, Wr2T, 6144, 768);

  k_gather<<<512, 256, 0, stream>>>(h, span, xs, xe);

  auto gemm = [&](const u16* A, int lda, const u16* BT, int ldb,
                  const float* bias, void* C, int ldc,
                  int M, int N, int K, int flags) {
    int mt = M / 128, nt = N / 128;
    k_gemm<<<mt * nt, 256, 0, stream>>>(A, lda, BT, ldb, bias, C, ldc, K, mt, flags);
  };

  // start/end MLPs on gathered rows (relu(x@W1+b1) @ W2 + b2), relu folded into cat
  gemm(xs, 768, Ws1T, 768, bs1, hs1, 3072, 512, 3072, 768, 1 | 2);
  gemm(hs1, 3072, Ws2T, 3072, bs2, cat, 1536, 512, 768, 3072, 1 | 2);
  gemm(xe, 768, We1T, 768, be1, he1, 3072, 512, 3072, 768, 1 | 2);
  gemm(he1, 3072, We2T, 3072, be2, cat + 768, 1536, 512, 768, 3072, 1 | 2);
  // entity MLP
  gemm(cat, 1536, Wo1T, 1536, bo1, enth, 6144, 512, 6144, 1536, 1 | 2);
  gemm(enth, 6144, Wo2T, 6144, bo2, ent, 768, 512, 768, 6144, 2);
  // low-rank pair projections: U = ent @ Wr1[:768] + br1 ; V = ent @ Wr1[768:]
  gemm(ent, 768, Wr1T, 1536, br1, Uf, 6144, 512, 6144, 768, 0);
  gemm(ent, 768, Wr1T + 768, 1536, nullptr, Vf, 6144, 512, 6144, 768, 0);
  // fused final pair GEMM -> out (f32)
  k_pair_gemm<<<252 * 6, 256, 0, stream>>>(Uf, Vf, Wr2T, br2, (float*)d_out);
}

// Round 3
// 719.740 us; speedup vs baseline: 1.8416x; 1.8416x over previous
//
#include <hip/hip_runtime.h>

typedef unsigned short u16;
typedef __attribute__((ext_vector_type(8))) short short8;
typedef __attribute__((ext_vector_type(4))) float f32x4;

#define DEVI static __device__ __forceinline__

DEVI u16 f2bf(float f) {
  unsigned u = __builtin_bit_cast(unsigned, f);
  u += 0x7FFFu + ((u >> 16) & 1u);   // RNE
  return (u16)(u >> 16);
}

DEVI float bf2f(u16 x) {
  unsigned u = ((unsigned)x) << 16;
  return __builtin_bit_cast(float, u);
}

DEVI unsigned cvtpk(float lo, float hi) {
  unsigned r;
  asm("v_cvt_pk_bf16_f32 %0, %1, %2" : "=v"(r) : "v"(lo), "v"(hi));
  return r;
}

DEVI void glds16(const void* g, void* l) {
  __builtin_amdgcn_global_load_lds(
      (const __attribute__((address_space(1))) unsigned*)g,
      (__attribute__((address_space(3))) unsigned*)l, 16, 0, 0);
}

// ---------------- transpose + f32->bf16 convert: W (K x N) -> WT (N x K) ----
__global__ void k_transpose_cvt(const float* __restrict__ W,
                                u16* __restrict__ WT, int K, int N) {
  __shared__ float t[32][33];
  int n0 = blockIdx.x * 32;
  int k0 = blockIdx.y * 32;
  int tx = threadIdx.x;  // 0..31
  int ty = threadIdx.y;  // 0..7
#pragma unroll
  for (int r = 0; r < 32; r += 8)
    t[ty + r][tx] = W[(size_t)(k0 + ty + r) * N + (n0 + tx)];
  __syncthreads();
#pragma unroll
  for (int r = 0; r < 32; r += 8)
    WT[(size_t)(n0 + ty + r) * K + (k0 + tx)] = f2bf(t[tx][ty + r]);
}

// ---------------- gather h rows at span starts/ends, cast to bf16 ----------
__global__ void k_gather(const float* __restrict__ h,
                         const int* __restrict__ span,
                         u16* __restrict__ xs, u16* __restrict__ xe) {
  int row = blockIdx.x;  // 0..511  (b*64+n)
  int b = row >> 6;
  int s = span[row * 2 + 0];
  int e = span[row * 2 + 1];
  const float* hs = h + ((size_t)b * 512 + s) * 768;
  const float* he = h + ((size_t)b * 512 + e) * 768;
  for (int d = threadIdx.x; d < 768; d += 256) {
    xs[(size_t)row * 768 + d] = f2bf(hs[d]);
    xe[(size_t)row * 768 + d] = f2bf(he[d]);
  }
}

// ---------------- generic bf16 MFMA GEMM: C = A * B (+bias)(relu) ----------
__global__ __launch_bounds__(256)
void k_gemm(const u16* __restrict__ A, int lda,
            const u16* __restrict__ BT, int ldb,
            const float* __restrict__ bias,
            void* __restrict__ C, int ldc,
            int K, int mtiles, int flags) {
  __shared__ __align__(16) u16 As[128 * 64];
  __shared__ __align__(16) u16 Bs[128 * 64];
  int tid = threadIdx.x;
  int lane = tid & 63;
  int wave = tid >> 6;
  int wr = (wave >> 1) * 64, wc = (wave & 1) * 64;
  int bx = blockIdx.x;
  int m0 = (bx % mtiles) * 128;
  int n0 = (bx / mtiles) * 128;
  const int lr = lane & 15, hi = lane >> 4;

  f32x4 acc[4][4] = {};

  for (int k0 = 0; k0 < K; k0 += 64) {
#pragma unroll
    for (int it = 0; it < 4; ++it) {
      int s = it * 256 + tid;     // 0..1023 16B-granules of the 128x64 tile
      int row = s >> 3, g = s & 7;
      int gc = (g ^ (row & 7)) * 8;  // pre-swizzled source column (elements)
      glds16(A + (size_t)(m0 + row) * lda + k0 + gc, (char*)As + s * 16);
      glds16(BT + (size_t)(n0 + row) * ldb + k0 + gc, (char*)Bs + s * 16);
    }
    __syncthreads();
#pragma unroll
    for (int kk = 0; kk < 2; ++kk) {
      short8 af[4], bf[4];
      int gk = kk * 4 + hi;
#pragma unroll
      for (int m = 0; m < 4; ++m) {
        int row = wr + m * 16 + lr;
        af[m] = *(const short8*)((const char*)As + row * 128 + ((gk ^ (row & 7)) * 16));
      }
#pragma unroll
      for (int n = 0; n < 4; ++n) {
        int row = wc + n * 16 + lr;
        bf[n] = *(const short8*)((const char*)Bs + row * 128 + ((gk ^ (row & 7)) * 16));
      }
#pragma unroll
      for (int m = 0; m < 4; ++m)
#pragma unroll
        for (int n = 0; n < 4; ++n)
          acc[m][n] = __builtin_amdgcn_mfma_f32_16x16x32_bf16(af[m], bf[n], acc[m][n], 0, 0, 0);
    }
    __syncthreads();
  }

  bool relu = flags & 1, obf = flags & 2;
#pragma unroll
  for (int n = 0; n < 4; ++n) {
    int col = n0 + wc + n * 16 + lr;
    float bv = bias ? bias[col] : 0.f;
#pragma unroll
    for (int m = 0; m < 4; ++m) {
#pragma unroll
      for (int r = 0; r < 4; ++r) {
        int row = m0 + wr + m * 16 + hi * 4 + r;
        float v = acc[m][n][r] + bv;
        if (relu) v = fmaxf(v, 0.f);
        if (obf) ((u16*)C)[(size_t)row * ldc + col] = f2bf(v);
        else     ((float*)C)[(size_t)row * ldc + col] = v;
      }
    }
  }
}

// ---------------- fused pair GEMM: out[m] = relu(U[i]+V[j]) @ Wr2 + br2 ----
// M = 32256 (8 x 4032 pairs), N = 768, K = 6144. Tile 128x256, BK=64,
// 512 threads / 8 waves. U,V bf16 (br1 folded into U). B double-buffered
// via global_load_lds; A built in regs -> LDS. Raw barrier #2 keeps
// prefetches (UV regs + B glds for t+1) in flight across MFMA(t).
__global__ __launch_bounds__(512, 4)
void k_pair_gemm(const u16* __restrict__ U, const u16* __restrict__ V,
                 const u16* __restrict__ Wr2T,  // 768 x 6144 bf16
                 const float* __restrict__ br2,
                 float* __restrict__ out) {
  __shared__ __align__(16) u16 As[128 * 64];       // 16 KB
  __shared__ __align__(16) u16 Bs[2][256 * 64];    // 64 KB
  int tid = threadIdx.x;
  int lane = tid & 63;
  int wave = tid >> 6;          // 0..7
  int wr = (wave >> 2) * 64;    // 0,64
  int wc = (wave & 3) * 64;     // 0..192
  const int lr = lane & 15, hi = lane >> 4;

  // bijective XCD swizzle (nwg=756, 756%8!=0 -> m204 formula)
  int nwg = gridDim.x;
  int orig = blockIdx.x;
  int xcd = orig & 7, rem = nwg & 7, qn = nwg >> 3;
  int wgid = (xcd < rem ? xcd * (qn + 1) : rem * (qn + 1) + (xcd - rem) * qn) + (orig >> 3);
  int mt = wgid % 252;
  int nt = wgid / 252;
  int m0 = mt * 128, n0 = nt * 256;

  // A-build mapping: thread owns row r, col-group q (16 cols of 64)
  int r = tid >> 2, q = tid & 3;
  int mrow = m0 + r;
  int b = mrow / 4032;
  int p = mrow - b * 4032;
  int i = p / 63;
  int j0 = p - i * 63;
  int j = j0 + (j0 >= i ? 1 : 0);
  const u16* uR = U + (size_t)(b * 64 + i) * 6144 + q * 16;
  const u16* vR = V + (size_t)(b * 64 + j) * 6144 + q * 16;
  char* aw0 = (char*)As + r * 128 + (((q * 2 + 0) ^ (r & 7)) * 16);
  char* aw1 = (char*)As + r * 128 + (((q * 2 + 1) ^ (r & 7)) * 16);

  f32x4 acc[4][4] = {};

  auto stageB = [&](int t, int buf) {
#pragma unroll
    for (int it = 0; it < 4; ++it) {
      int s = it * 512 + tid;      // 2048 granules of 256x64 tile
      int row = s >> 3, g = s & 7;
      int gc = (g ^ (row & 7)) * 8;
      glds16(Wr2T + (size_t)(n0 + row) * 6144 + t * 64 + gc,
             (char*)Bs[buf] + s * 16);
    }
  };

  // prologue: B(0) staged, UV(0) in regs
  stageB(0, 0);
  short8 ua = *(const short8*)(uR);
  short8 ub = *(const short8*)(uR + 8);
  short8 vva = *(const short8*)(vR);
  short8 vvb = *(const short8*)(vR + 8);

  for (int t = 0; t < 96; ++t) {
    // build A(t) fragment in regs (16 elems -> 8 packed u32)
    unsigned w0[4], w1[4];
#pragma unroll
    for (int e = 0; e < 4; ++e) {
      float a0 = fmaxf(bf2f((u16)ua[2 * e])     + bf2f((u16)vva[2 * e]), 0.f);
      float a1 = fmaxf(bf2f((u16)ua[2 * e + 1]) + bf2f((u16)vva[2 * e + 1]), 0.f);
      w0[e] = cvtpk(a0, a1);
      float b0 = fmaxf(bf2f((u16)ub[2 * e])     + bf2f((u16)vvb[2 * e]), 0.f);
      float b1 = fmaxf(bf2f((u16)ub[2 * e + 1]) + bf2f((u16)vvb[2 * e + 1]), 0.f);
      w1[e] = cvtpk(b0, b1);
    }
    __syncthreads();                     // #1: all reads of As/Bs[t&1] done; B(t) drained
    *(uint4*)aw0 = *(uint4*)w0;          // swizzled A writes
    *(uint4*)aw1 = *(uint4*)w1;
    if (t + 1 < 96) {                    // prefetch t+1 (flies across MFMA(t))
      ua  = *(const short8*)(uR + (t + 1) * 64);
      ub  = *(const short8*)(uR + (t + 1) * 64 + 8);
      vva = *(const short8*)(vR + (t + 1) * 64);
      vvb = *(const short8*)(vR + (t + 1) * 64 + 8);
      stageB(t + 1, (t + 1) & 1);
    }
    asm volatile("s_waitcnt lgkmcnt(0)\n\ts_barrier" ::: "memory");  // #2: no vmcnt drain
    __builtin_amdgcn_sched_barrier(0);

    const u16* Bc = Bs[t & 1];
#pragma unroll
    for (int kk = 0; kk < 2; ++kk) {
      short8 af[4], bf[4];
      int gk = kk * 4 + hi;
#pragma unroll
      for (int m = 0; m < 4; ++m) {
        int row = wr + m * 16 + lr;
        af[m] = *(const short8*)((const char*)As + row * 128 + ((gk ^ (row & 7)) * 16));
      }
#pragma unroll
      for (int n = 0; n < 4; ++n) {
        int row = wc + n * 16 + lr;
        bf[n] = *(const short8*)((const char*)Bc + row * 128 + ((gk ^ (row & 7)) * 16));
      }
#pragma unroll
      for (int m = 0; m < 4; ++m)
#pragma unroll
        for (int n = 0; n < 4; ++n)
          acc[m][n] = __builtin_amdgcn_mfma_f32_16x16x32_bf16(af[m], bf[n], acc[m][n], 0, 0, 0);
    }
  }

#pragma unroll
  for (int n = 0; n < 4; ++n) {
    int col = n0 + wc + n * 16 + lr;
    float bv = br2[col];
#pragma unroll
    for (int m = 0; m < 4; ++m) {
#pragma unroll
      for (int rg = 0; rg < 4; ++rg) {
        int row = m0 + wr + m * 16 + hi * 4 + rg;
        out[(size_t)row * 768 + col] = acc[m][n][rg] + bv;
      }
    }
  }
}

// ---------------- workspace layout (bytes) ---------------------------------
constexpr size_t OFF_Ws1T = 0;
constexpr size_t OFF_Ws2T = OFF_Ws1T + (size_t)3072 * 768 * 2;
constexpr size_t OFF_We1T = OFF_Ws2T + (size_t)768 * 3072 * 2;
constexpr size_t OFF_We2T = OFF_We1T + (size_t)3072 * 768 * 2;
constexpr size_t OFF_Wo1T = OFF_We2T + (size_t)768 * 3072 * 2;
constexpr size_t OFF_Wo2T = OFF_Wo1T + (size_t)6144 * 1536 * 2;
constexpr size_t OFF_Wr1T = OFF_Wo2T + (size_t)768 * 6144 * 2;
constexpr size_t OFF_Wr2T = OFF_Wr1T + (size_t)6144 * 1536 * 2;
constexpr size_t OFF_XS   = OFF_Wr2T + (size_t)768 * 6144 * 2;
constexpr size_t OFF_XE   = OFF_XS + (size_t)512 * 768 * 2;
constexpr size_t OFF_HS1  = OFF_XE + (size_t)512 * 768 * 2;
constexpr size_t OFF_HE1  = OFF_HS1 + (size_t)512 * 3072 * 2;
constexpr size_t OFF_CAT  = OFF_HE1 + (size_t)512 * 3072 * 2;
constexpr size_t OFF_ENTH = OFF_CAT + (size_t)512 * 1536 * 2;
constexpr size_t OFF_ENT  = OFF_ENTH + (size_t)512 * 6144 * 2;
constexpr size_t OFF_U    = OFF_ENT + (size_t)512 * 768 * 2;
constexpr size_t OFF_V    = OFF_U + (size_t)512 * 6144 * 2;

extern "C" void kernel_launch(void* const* d_in, const int* in_sizes, int n_in,
                              void* d_out, int out_size, void* d_ws, size_t ws_size,
                              hipStream_t stream) {
  const float* h = (const float*)d_in[0];
  const int* span = (const int*)d_in[1];   // int inputs arrive as int32
  const float* Ws1 = (const float*)d_in[2];
  const float* bs1 = (const float*)d_in[3];
  const float* Ws2 = (const float*)d_in[4];
  const float* bs2 = (const float*)d_in[5];
  const float* We1 = (const float*)d_in[6];
  const float* be1 = (const float*)d_in[7];
  const float* We2 = (const float*)d_in[8];
  const float* be2 = (const float*)d_in[9];
  const float* Wo1 = (const float*)d_in[10];
  const float* bo1 = (const float*)d_in[11];
  const float* Wo2 = (const float*)d_in[12];
  const float* bo2 = (const float*)d_in[13];
  const float* Wr1 = (const float*)d_in[14];
  const float* br1 = (const float*)d_in[15];
  const float* Wr2 = (const float*)d_in[16];
  const float* br2 = (const float*)d_in[17];

  char* ws = (char*)d_ws;
  u16* Ws1T = (u16*)(ws + OFF_Ws1T);
  u16* Ws2T = (u16*)(ws + OFF_Ws2T);
  u16* We1T = (u16*)(ws + OFF_We1T);
  u16* We2T = (u16*)(ws + OFF_We2T);
  u16* Wo1T = (u16*)(ws + OFF_Wo1T);
  u16* Wo2T = (u16*)(ws + OFF_Wo2T);
  u16* Wr1T = (u16*)(ws + OFF_Wr1T);
  u16* Wr2T = (u16*)(ws + OFF_Wr2T);
  u16* xs   = (u16*)(ws + OFF_XS);
  u16* xe   = (u16*)(ws + OFF_XE);
  u16* hs1  = (u16*)(ws + OFF_HS1);
  u16* he1  = (u16*)(ws + OFF_HE1);
  u16* cat  = (u16*)(ws + OFF_CAT);
  u16* enth = (u16*)(ws + OFF_ENTH);
  u16* ent  = (u16*)(ws + OFF_ENT);
  u16* Ub   = (u16*)(ws + OFF_U);
  u16* Vb   = (u16*)(ws + OFF_V);

  dim3 tb(32, 8);
  k_transpose_cvt<<<dim3(3072 / 32, 768 / 32), tb, 0, stream>>>(Ws1, Ws1T, 768, 3072);
  k_transpose_cvt<<<dim3(768 / 32, 3072 / 32), tb, 0, stream>>>(Ws2, Ws2T, 3072, 768);
  k_transpose_cvt<<<dim3(3072 / 32, 768 / 32), tb, 0, stream>>>(We1, We1T, 768, 3072);
  k_transpose_cvt<<<dim3(768 / 32, 3072 / 32), tb, 0, stream>>>(We2, We2T, 3072, 768);
  k_transpose_cvt<<<dim3(6144 / 32, 1536 / 32), tb, 0, stream>>>(Wo1, Wo1T, 1536, 6144);
  k_transpose_cvt<<<dim3(768 / 32, 6144 / 32), tb, 0, stream>>>(Wo2, Wo2T, 6144, 768);
  k_transpose_cvt<<<dim3(6144 / 32, 1536 / 32), tb, 0, stream>>>(Wr1, Wr1T, 1536, 6144);
  k_transpose_cvt<<<dim3(768 / 32, 6144 / 32), tb, 0, stream>>>(Wr2, Wr2T, 6144, 768);

  k_gather<<<512, 256, 0, stream>>>(h, span, xs, xe);

  auto gemm = [&](const u16* A, int lda, const u16* BT, int ldb,
                  const float* bias, void* C, int ldc,
                  int M, int N, int K, int flags) {
    int mt = M / 128, nt = N / 128;
    k_gemm<<<mt * nt, 256, 0, stream>>>(A, lda, BT, ldb, bias, C, ldc, K, mt, flags);
  };

  // start/end MLPs on gathered rows; relu folded into cat
  gemm(xs, 768, Ws1T, 768, bs1, hs1, 3072, 512, 3072, 768, 1 | 2);
  gemm(hs1, 3072, Ws2T, 3072, bs2, cat, 1536, 512, 768, 3072, 1 | 2);
  gemm(xe, 768, We1T, 768, be1, he1, 3072, 512, 3072, 768, 1 | 2);
  gemm(he1, 3072, We2T, 3072, be2, cat + 768, 1536, 512, 768, 3072, 1 | 2);
  // entity MLP
  gemm(cat, 1536, Wo1T, 1536, bo1, enth, 6144, 512, 6144, 1536, 1 | 2);
  gemm(enth, 6144, Wo2T, 6144, bo2, ent, 768, 512, 768, 6144, 2);
  // low-rank pair projections (bf16 out): U = ent@Wr1[:768]+br1 ; V = ent@Wr1[768:]
  gemm(ent, 768, Wr1T, 1536, br1, Ub, 6144, 512, 6144, 768, 2);
  gemm(ent, 768, Wr1T + 768, 1536, nullptr, Vb, 6144, 512, 6144, 768, 2);
  // fused final pair GEMM -> out (f32)
  k_pair_gemm<<<252 * 3, 512, 0, stream>>>(Ub, Vb, Wr2T, br2, (float*)d_out);
}